// Round 1
// baseline (94.191 us; speedup 1.0000x reference)
//
#include <hip/hip_runtime.h>
#include <math.h>

#define NPTS 200
#define WAVES_PER_BLOCK 4

// --- 1D cell setup: u = clip((p+1)/2,0,1)*R; i0 = clip(floor(u),0,R-1); f = u - i0
__device__ __forceinline__ void cell1d(int R, float p, int& i0, float& f) {
    float u = fminf(fmaxf((p + 1.0f) * 0.5f, 0.0f), 1.0f) * (float)R;
    int i = (int)floorf(u);
    if (i > R - 1) i = R - 1;      // i >= 0 guaranteed (u >= 0)
    i0 = i;
    f = u - (float)i;
}

// Trilinear interp of feature 0 only (label channel). Table rows are 4 floats.
__device__ __forceinline__ float trilerp_label(const float* __restrict__ tab, int R,
                                               float px, float py, float pz) {
    int ix, iy, iz; float fx, fy, fz;
    cell1d(R, px, ix, fx);
    cell1d(R, py, iy, fy);
    cell1d(R, pz, iz, fz);
    const int Rp1 = R + 1;
    const int sx = Rp1 * Rp1;
    const int base = (ix * Rp1 + iy) * Rp1 + iz;
    float v000 = tab[4 * base];
    float v001 = tab[4 * (base + 1)];
    float v010 = tab[4 * (base + Rp1)];
    float v011 = tab[4 * (base + Rp1 + 1)];
    float v100 = tab[4 * (base + sx)];
    float v101 = tab[4 * (base + sx + 1)];
    float v110 = tab[4 * (base + sx + Rp1)];
    float v111 = tab[4 * (base + sx + Rp1 + 1)];
    float gx = 1.0f - fx, gy = 1.0f - fy, gz = 1.0f - fz;
    float c00 = v000 * gz + v001 * fz;
    float c01 = v010 * gz + v011 * fz;
    float c10 = v100 * gz + v101 * fz;
    float c11 = v110 * gz + v111 * fz;
    float c0 = c00 * gy + c01 * fy;
    float c1 = c10 * gy + c11 * fy;
    return c0 * gx + c1 * fx;
}

// Trilinear interp of features 1..3 (rgb channels), accumulated into out3[0..2].
__device__ __forceinline__ void trilerp_rgb(const float* __restrict__ tab, int R,
                                            float px, float py, float pz,
                                            float* out3) {
    int ix, iy, iz; float fx, fy, fz;
    cell1d(R, px, ix, fx);
    cell1d(R, py, iy, fy);
    cell1d(R, pz, iz, fz);
    const int Rp1 = R + 1;
    const int sx = Rp1 * Rp1;
    const int base = (ix * Rp1 + iy) * Rp1 + iz;
    float gx = 1.0f - fx, gy = 1.0f - fy, gz = 1.0f - fz;
    float wx[2] = {gx, fx}, wy[2] = {gy, fy}, wz[2] = {gz, fz};
    float a0 = 0.0f, a1 = 0.0f, a2 = 0.0f;
#pragma unroll
    for (int dx = 0; dx < 2; ++dx) {
#pragma unroll
        for (int dy = 0; dy < 2; ++dy) {
#pragma unroll
            for (int dz = 0; dz < 2; ++dz) {
                int idx = base + dx * sx + dy * Rp1 + dz;
                float4 v = *reinterpret_cast<const float4*>(tab + 4 * idx);
                float w = wx[dx] * wy[dy] * wz[dz];
                a0 += w * v.y;
                a1 += w * v.z;
                a2 += w * v.w;
            }
        }
    }
    out3[0] = a0;
    out3[1] = a1;
    out3[2] = a2;
}

__global__ __launch_bounds__(WAVES_PER_BLOCK * 64)
void rays_kernel(const float* __restrict__ x,
                 const float* __restrict__ g0,
                 const float* __restrict__ g1,
                 const float* __restrict__ g2,
                 const float* __restrict__ wl,   // (3,1) flat
                 const float* __restrict__ bl,   // (1,)
                 const float* __restrict__ wr,   // (9,3) flat row-major
                 const float* __restrict__ br,   // (3,)
                 float* __restrict__ out_hits,   // (n,)
                 float* __restrict__ out_rgb,    // (n,3)
                 int n)
{
    const int wave = (int)((blockIdx.x * blockDim.x + threadIdx.x) >> 6);
    const int lane = (int)(threadIdx.x & 63);
    if (wave >= n) return;

    // Ray endpoints (wave-uniform loads; every lane computes the same values).
    const float th1 = x[wave * 4 + 0];
    const float ph1 = x[wave * 4 + 1];
    const float th2 = x[wave * 4 + 2];
    const float ph2 = x[wave * 4 + 3];
    float s1 = __sinf(th1), c1 = __cosf(th1);
    float s2 = __sinf(th2), c2 = __cosf(th2);
    float p1x = s1 * __cosf(ph1), p1y = s1 * __sinf(ph1), p1z = c1;
    float p2x = s2 * __cosf(ph2), p2y = s2 * __sinf(ph2), p2z = c2;
    const float dxr = p2x - p1x, dyr = p2y - p1y, dzr = p2z - p1z;

    const float wl0 = wl[0], wl1 = wl[1], wl2 = wl[2], bl0 = bl[0];
    const float inv = 1.0f / (float)(NPTS - 1);

    float maxlogit = -INFINITY;
    int firsthit = NPTS;  // sentinel: "no hit"

    for (int t = lane; t < NPTS; t += 64) {
        float tt = (float)t * inv;
        float px = p1x + dxr * tt;
        float py = p1y + dyr * tt;
        float pz = p1z + dzr * tt;
        float l0 = trilerp_label(g0, 8,  px, py, pz);
        float l1 = trilerp_label(g1, 16, px, py, pz);
        float l2 = trilerp_label(g2, 32, px, py, pz);
        float logit = bl0 + wl0 * l0 + wl1 * l1 + wl2 * l2;
        maxlogit = fmaxf(maxlogit, logit);
        if (logit > 0.0f && t < firsthit) firsthit = t;
    }

    // Wave-wide butterfly reduction (64 lanes).
#pragma unroll
    for (int m = 32; m >= 1; m >>= 1) {
        maxlogit = fmaxf(maxlogit, __shfl_xor(maxlogit, m, 64));
        firsthit = min(firsthit, __shfl_xor(firsthit, m, 64));
    }

    if (lane == 0) {
        out_hits[wave] = 1.0f / (1.0f + __expf(-maxlogit));

        const int tsel = (firsthit >= NPTS) ? 0 : firsthit;
        float tt = (float)tsel * inv;
        float px = p1x + dxr * tt;
        float py = p1y + dyr * tt;
        float pz = p1z + dzr * tt;
        float feat[9];
        trilerp_rgb(g0, 8,  px, py, pz, &feat[0]);
        trilerp_rgb(g1, 16, px, py, pz, &feat[3]);
        trilerp_rgb(g2, 32, px, py, pz, &feat[6]);
#pragma unroll
        for (int c = 0; c < 3; ++c) {
            float acc = br[c];
#pragma unroll
            for (int f = 0; f < 9; ++f) acc += feat[f] * wr[f * 3 + c];
            out_rgb[wave * 3 + c] = 1.0f / (1.0f + __expf(-acc));
        }
    }
}

extern "C" void kernel_launch(void* const* d_in, const int* in_sizes, int n_in,
                              void* d_out, int out_size, void* d_ws, size_t ws_size,
                              hipStream_t stream) {
    const float* x  = (const float*)d_in[0];
    const float* g0 = (const float*)d_in[1];
    const float* g1 = (const float*)d_in[2];
    const float* g2 = (const float*)d_in[3];
    const float* wl = (const float*)d_in[4];
    const float* bl = (const float*)d_in[5];
    const float* wr = (const float*)d_in[6];
    const float* br = (const float*)d_in[7];

    const int n = in_sizes[0] / 4;             // BATCH rays
    float* out_hits = (float*)d_out;           // n floats
    float* out_rgb  = (float*)d_out + n;       // n*3 floats

    const int block = WAVES_PER_BLOCK * 64;
    const int grid = (n + WAVES_PER_BLOCK - 1) / WAVES_PER_BLOCK;
    rays_kernel<<<grid, block, 0, stream>>>(x, g0, g1, g2, wl, bl, wr, br,
                                            out_hits, out_rgb, n);
}

// Round 2
// 38.466 us; speedup vs baseline: 2.4487x; 2.4487x over previous
//
#include <hip/hip_runtime.h>
#include <math.h>

#define NPTS 200
#define NRAYS 32768

// Packed-pair table sizes (float4 entries)
#define N0 729        // 9^3
#define N1 4913       // 17^3
#define N2 42875      // 35^3
#define OFF1 (N0)
#define OFF2 (N0 + N1)
#define NTOT (N0 + N1 + N2)

// ---------------- prep: build packed label tables ----------------
// P[(ix*Rp1+iy)*Rp1+iz] = { L(ix,iy,iz), L(ix,iy,iz+1), L(ix,iy+1,iz), L(ix,iy+1,iz+1) }
// where L = grid[...][0] (label channel).
template<int R>
__device__ __forceinline__ void build_pairs(const float* __restrict__ g,
                                            float4* __restrict__ P, int i) {
    constexpr int Rp1 = R + 1;
    int iz = i % Rp1;
    int r  = i / Rp1;
    int iy = r % Rp1;
    int ix = r / Rp1;
    int izp = min(iz + 1, R);
    int iyp = min(iy + 1, R);
    float4 v;
    v.x = g[4 * ((ix * Rp1 + iy ) * Rp1 + iz )];
    v.y = g[4 * ((ix * Rp1 + iy ) * Rp1 + izp)];
    v.z = g[4 * ((ix * Rp1 + iyp) * Rp1 + iz )];
    v.w = g[4 * ((ix * Rp1 + iyp) * Rp1 + izp)];
    P[i] = v;
}

__global__ __launch_bounds__(256)
void prep_kernel(const float* __restrict__ g0, const float* __restrict__ g1,
                 const float* __restrict__ g2, float4* __restrict__ ws) {
    int i = blockIdx.x * blockDim.x + threadIdx.x;
    if (i < N0)            build_pairs<8 >(g0, ws,        i);
    else if (i < OFF2)     build_pairs<16>(g1, ws + OFF1, i - OFF1);
    else if (i < NTOT)     build_pairs<32>(g2, ws + OFF2, i - OFF2);
}

// ---------------- label interp from packed table ----------------
template<int R>
__device__ __forceinline__ float lerp_packed(const float4* __restrict__ P,
                                             float cx, float cy, float cz) {
    constexpr int Rp1 = R + 1;
    float ux = cx * (float)R, uy = cy * (float)R, uz = cz * (float)R;
    int ix = min((int)ux, R - 1);   // u >= 0, trunc == floor
    int iy = min((int)uy, R - 1);
    int iz = min((int)uz, R - 1);
    float fx = ux - (float)ix, fy = uy - (float)iy, fz = uz - (float)iz;
    int idx = (ix * Rp1 + iy) * Rp1 + iz;
    float4 q0 = P[idx];
    float4 q1 = P[idx + Rp1 * Rp1];
    // lerp over x
    float mx = q0.x + fx * (q1.x - q0.x);
    float my = q0.y + fx * (q1.y - q0.y);
    float mz = q0.z + fx * (q1.z - q0.z);
    float mw = q0.w + fx * (q1.w - q0.w);
    // lerp over z then y
    float r0 = mx + fz * (my - mx);
    float r1 = mz + fz * (mw - mz);
    return r0 + fy * (r1 - r0);
}

// RGB corner contribution: this lane's corner (dx,dy,dz) for one level.
template<int R>
__device__ __forceinline__ void rgb_corner(const float* __restrict__ g,
                                           float cx, float cy, float cz,
                                           int dx, int dy, int dz,
                                           float* f3) {
    constexpr int Rp1 = R + 1;
    float ux = cx * (float)R, uy = cy * (float)R, uz = cz * (float)R;
    int ix = min((int)ux, R - 1);
    int iy = min((int)uy, R - 1);
    int iz = min((int)uz, R - 1);
    float fx = ux - (float)ix, fy = uy - (float)iy, fz = uz - (float)iz;
    int idx = ((ix + dx) * Rp1 + (iy + dy)) * Rp1 + (iz + dz);
    float w = (dx ? fx : 1.0f - fx) * (dy ? fy : 1.0f - fy) * (dz ? fz : 1.0f - fz);
    float4 v = *reinterpret_cast<const float4*>(g + 4 * idx);
    f3[0] = w * v.y;
    f3[1] = w * v.z;
    f3[2] = w * v.w;
}

// ---------------- main: 8 lanes per ray, 8 rays per wave ----------------
__global__ __launch_bounds__(256)
void rays_kernel(const float* __restrict__ x,
                 const float4* __restrict__ P0,
                 const float4* __restrict__ P1,
                 const float4* __restrict__ P2,
                 const float* __restrict__ g0,
                 const float* __restrict__ g1,
                 const float* __restrict__ g2,
                 const float* __restrict__ wl,
                 const float* __restrict__ bl,
                 const float* __restrict__ wr,
                 const float* __restrict__ br,
                 float* __restrict__ out_hits,
                 float* __restrict__ out_rgb,
                 int n)
{
    const int tid = blockIdx.x * blockDim.x + threadIdx.x;
    const int ray = tid >> 3;
    const int sub = (int)(threadIdx.x & 7);
    if (ray >= n) return;

    const float th1 = x[ray * 4 + 0];
    const float ph1 = x[ray * 4 + 1];
    const float th2 = x[ray * 4 + 2];
    const float ph2 = x[ray * 4 + 3];
    float s1 = __sinf(th1), c1 = __cosf(th1);
    float s2 = __sinf(th2), c2 = __cosf(th2);
    float p1x = s1 * __cosf(ph1), p1y = s1 * __sinf(ph1), p1z = c1;
    float p2x = s2 * __cosf(ph2), p2y = s2 * __sinf(ph2), p2z = c2;
    const float dxr = p2x - p1x, dyr = p2y - p1y, dzr = p2z - p1z;

    const float wl0 = wl[0], wl1 = wl[1], wl2 = wl[2], bl0 = bl[0];
    const float inv = 1.0f / (float)(NPTS - 1);

    float maxlogit = -INFINITY;
    int firsthit = NPTS;

#pragma unroll 5
    for (int i = 0; i < 25; ++i) {
        int t = i * 8 + sub;
        float tt = (float)t * inv;
        float px = p1x + dxr * tt;
        float py = p1y + dyr * tt;
        float pz = p1z + dzr * tt;
        // shared clamp01((p+1)/2)
        float cx = fminf(fmaxf(px * 0.5f + 0.5f, 0.0f), 1.0f);
        float cy = fminf(fmaxf(py * 0.5f + 0.5f, 0.0f), 1.0f);
        float cz = fminf(fmaxf(pz * 0.5f + 0.5f, 0.0f), 1.0f);
        float l0 = lerp_packed<8 >(P0, cx, cy, cz);
        float l1 = lerp_packed<16>(P1, cx, cy, cz);
        float l2 = lerp_packed<32>(P2, cx, cy, cz);
        float logit = bl0 + wl0 * l0 + wl1 * l1 + wl2 * l2;
        maxlogit = fmaxf(maxlogit, logit);
        if (logit > 0.0f) firsthit = min(firsthit, t);
    }

    // reduce across the 8-lane group
#pragma unroll
    for (int m = 4; m >= 1; m >>= 1) {
        maxlogit = fmaxf(maxlogit, __shfl_xor(maxlogit, m, 64));
        firsthit = min(firsthit, __shfl_xor(firsthit, m, 64));
    }

    // ---- RGB at first-hit point, corner-parallel across the 8 lanes ----
    const int tsel = (firsthit >= NPTS) ? 0 : firsthit;
    {
        float tt = (float)tsel * inv;
        float px = p1x + dxr * tt;
        float py = p1y + dyr * tt;
        float pz = p1z + dzr * tt;
        float cx = fminf(fmaxf(px * 0.5f + 0.5f, 0.0f), 1.0f);
        float cy = fminf(fmaxf(py * 0.5f + 0.5f, 0.0f), 1.0f);
        float cz = fminf(fmaxf(pz * 0.5f + 0.5f, 0.0f), 1.0f);
        const int dx = (sub >> 2) & 1, dy = (sub >> 1) & 1, dz = sub & 1;
        float feat[9];
        rgb_corner<8 >(g0, cx, cy, cz, dx, dy, dz, &feat[0]);
        rgb_corner<16>(g1, cx, cy, cz, dx, dy, dz, &feat[3]);
        rgb_corner<32>(g2, cx, cy, cz, dx, dy, dz, &feat[6]);
        // sum the 8 corners across the group
#pragma unroll
        for (int m = 4; m >= 1; m >>= 1) {
#pragma unroll
            for (int k = 0; k < 9; ++k)
                feat[k] += __shfl_xor(feat[k], m, 64);
        }
        if (sub == 0) {
            out_hits[ray] = 1.0f / (1.0f + __expf(-maxlogit));
#pragma unroll
            for (int c = 0; c < 3; ++c) {
                float acc = br[c];
#pragma unroll
                for (int f = 0; f < 9; ++f) acc += feat[f] * wr[f * 3 + c];
                out_rgb[ray * 3 + c] = 1.0f / (1.0f + __expf(-acc));
            }
        }
    }
}

extern "C" void kernel_launch(void* const* d_in, const int* in_sizes, int n_in,
                              void* d_out, int out_size, void* d_ws, size_t ws_size,
                              hipStream_t stream) {
    const float* x  = (const float*)d_in[0];
    const float* g0 = (const float*)d_in[1];
    const float* g1 = (const float*)d_in[2];
    const float* g2 = (const float*)d_in[3];
    const float* wl = (const float*)d_in[4];
    const float* bl = (const float*)d_in[5];
    const float* wr = (const float*)d_in[6];
    const float* br = (const float*)d_in[7];

    const int n = in_sizes[0] / 4;
    float* out_hits = (float*)d_out;
    float* out_rgb  = (float*)d_out + n;

    float4* P = (float4*)d_ws;   // needs NTOT*16 = 776272 B of scratch

    prep_kernel<<<(NTOT + 255) / 256, 256, 0, stream>>>(g0, g1, g2, P);

    const int block = 256;                 // 32 rays per block
    const int grid = (n * 8 + block - 1) / block;
    rays_kernel<<<grid, block, 0, stream>>>(x, P, P + OFF1, P + OFF2,
                                            g0, g1, g2, wl, bl, wr, br,
                                            out_hits, out_rgb, n);
}

// Round 3
// 21.981 us; speedup vs baseline: 4.2851x; 1.7500x over previous
//
#include <hip/hip_runtime.h>
#include <math.h>

#define NPTS 200
#define L33   33
#define L33SQ 1089        // 33*33
#define NLAT  35937       // 33^3

// ---------- prep: trilinear label (channel 0) of grid g at u in [0,R]^3 ----------
template<int R>
__device__ __forceinline__ float tri_label(const float* __restrict__ g,
                                           float ux, float uy, float uz) {
    constexpr int Rp1 = R + 1;
    constexpr int SX  = Rp1 * Rp1;
    int ix = min((int)ux, R - 1);
    int iy = min((int)uy, R - 1);
    int iz = min((int)uz, R - 1);
    float fx = ux - (float)ix, fy = uy - (float)iy, fz = uz - (float)iz;
    int b = (ix * Rp1 + iy) * Rp1 + iz;
    float v000 = g[4*b],            v001 = g[4*(b+1)];
    float v010 = g[4*(b+Rp1)],      v011 = g[4*(b+Rp1+1)];
    float v100 = g[4*(b+SX)],       v101 = g[4*(b+SX+1)];
    float v110 = g[4*(b+SX+Rp1)],   v111 = g[4*(b+SX+Rp1+1)];
    float c00 = fmaf(fz, v001 - v000, v000);
    float c01 = fmaf(fz, v011 - v010, v010);
    float c10 = fmaf(fz, v101 - v100, v100);
    float c11 = fmaf(fz, v111 - v110, v110);
    float c0  = fmaf(fy, c01 - c00, c00);
    float c1  = fmaf(fy, c11 - c10, c10);
    return fmaf(fx, c1 - c0, c0);
}

// combined logit field at 33^3 lattice point (jx,jy,jz)
__device__ __forceinline__ float T_eval(const float* __restrict__ g0,
                                        const float* __restrict__ g1,
                                        const float* __restrict__ g2,
                                        float wl0, float wl1, float wl2, float bl0,
                                        int jx, int jy, int jz) {
    float fx = (float)jx, fy = (float)jy, fz = (float)jz;
    float L0 = tri_label<8 >(g0, fx * 0.25f, fy * 0.25f, fz * 0.25f);  // exact quarters
    float L1 = tri_label<16>(g1, fx * 0.5f,  fy * 0.5f,  fz * 0.5f);   // exact halves
    float L2 = g2[4 * ((jx * L33 + jy) * L33 + jz)];
    return bl0 + wl0 * L0 + wl1 * L1 + wl2 * L2;
}

// P[(ix*33+iy)*33+iz] = { T(ix,iy,iz), T(ix,iy,iz+1), T(ix,iy+1,iz), T(ix,iy+1,iz+1) }
__global__ __launch_bounds__(256)
void prep_kernel(const float* __restrict__ g0, const float* __restrict__ g1,
                 const float* __restrict__ g2, const float* __restrict__ wl,
                 const float* __restrict__ bl, float4* __restrict__ P) {
    int i = blockIdx.x * blockDim.x + threadIdx.x;
    if (i >= NLAT) return;
    int iz = i % L33;
    int r  = i / L33;
    int iy = r % L33;
    int ix = r / L33;
    int izp = min(iz + 1, L33 - 1);
    int iyp = min(iy + 1, L33 - 1);
    float wl0 = wl[0], wl1 = wl[1], wl2 = wl[2], bl0 = bl[0];
    float4 v;
    v.x = T_eval(g0, g1, g2, wl0, wl1, wl2, bl0, ix, iy,  iz );
    v.y = T_eval(g0, g1, g2, wl0, wl1, wl2, bl0, ix, iy,  izp);
    v.z = T_eval(g0, g1, g2, wl0, wl1, wl2, bl0, ix, iyp, iz );
    v.w = T_eval(g0, g1, g2, wl0, wl1, wl2, bl0, ix, iyp, izp);
    P[i] = v;
}

// ---------- RGB corner contribution (round-2 path, 1 point per ray) ----------
template<int R>
__device__ __forceinline__ void rgb_corner(const float* __restrict__ g,
                                           float cx, float cy, float cz,
                                           int dx, int dy, int dz,
                                           float* f3) {
    constexpr int Rp1 = R + 1;
    float ux = cx * (float)R, uy = cy * (float)R, uz = cz * (float)R;
    int ix = min((int)ux, R - 1);
    int iy = min((int)uy, R - 1);
    int iz = min((int)uz, R - 1);
    float fx = ux - (float)ix, fy = uy - (float)iy, fz = uz - (float)iz;
    int idx = ((ix + dx) * Rp1 + (iy + dy)) * Rp1 + (iz + dz);
    float w = (dx ? fx : 1.0f - fx) * (dy ? fy : 1.0f - fy) * (dz ? fz : 1.0f - fz);
    float4 v = *reinterpret_cast<const float4*>(g + 4 * idx);
    f3[0] = w * v.y;
    f3[1] = w * v.z;
    f3[2] = w * v.w;
}

// ---------- main: 8 lanes per ray, single combined lerp per point ----------
__global__ __launch_bounds__(256)
void rays_kernel(const float* __restrict__ x,
                 const float4* __restrict__ P,
                 const float* __restrict__ g0,
                 const float* __restrict__ g1,
                 const float* __restrict__ g2,
                 const float* __restrict__ wr,
                 const float* __restrict__ br,
                 float* __restrict__ out_hits,
                 float* __restrict__ out_rgb,
                 int n)
{
    const int tid = blockIdx.x * blockDim.x + threadIdx.x;
    const int ray = tid >> 3;
    const int sub = (int)(threadIdx.x & 7);
    if (ray >= n) return;

    const float th1 = x[ray * 4 + 0];
    const float ph1 = x[ray * 4 + 1];
    const float th2 = x[ray * 4 + 2];
    const float ph2 = x[ray * 4 + 3];
    float s1 = __sinf(th1), c1 = __cosf(th1);
    float s2 = __sinf(th2), c2 = __cosf(th2);
    float p1x = s1 * __cosf(ph1), p1y = s1 * __sinf(ph1), p1z = c1;
    float p2x = s2 * __cosf(ph2), p2y = s2 * __sinf(ph2), p2z = c2;
    const float dxr = p2x - p1x, dyr = p2y - p1y, dzr = p2z - p1z;

    const float inv = 1.0f / (float)(NPTS - 1);
    const float sc  = 16.0f * inv;           // du per unit t, in 33-grid units

    // u(t) = (p+1)*16 at t, advanced by exact integer tf
    const float bx = fmaf(p1x, 16.0f, 16.0f);
    const float by = fmaf(p1y, 16.0f, 16.0f);
    const float bz = fmaf(p1z, 16.0f, 16.0f);
    const float dux = dxr * sc, duy = dyr * sc, duz = dzr * sc;

    float tf = (float)sub;                   // exact small ints
    float maxlogit = -INFINITY;
    int firsthit = NPTS;

#pragma unroll 5
    for (int i = 0; i < 25; ++i) {
        float ux = fminf(fmaxf(fmaf(tf, dux, bx), 0.0f), 32.0f);
        float uy = fminf(fmaxf(fmaf(tf, duy, by), 0.0f), 32.0f);
        float uz = fminf(fmaxf(fmaf(tf, duz, bz), 0.0f), 32.0f);
        int ix = min((int)ux, 31);
        int iy = min((int)uy, 31);
        int iz = min((int)uz, 31);
        float fx = ux - (float)ix;
        float fy = uy - (float)iy;
        float fz = uz - (float)iz;
        int idx = (ix * L33 + iy) * L33 + iz;
        float4 q0 = P[idx];
        float4 q1 = P[idx + L33SQ];
        float mx = fmaf(fx, q1.x - q0.x, q0.x);
        float my = fmaf(fx, q1.y - q0.y, q0.y);
        float mz = fmaf(fx, q1.z - q0.z, q0.z);
        float mw = fmaf(fx, q1.w - q0.w, q0.w);
        float r0 = fmaf(fz, my - mx, mx);
        float r1 = fmaf(fz, mw - mz, mz);
        float logit = fmaf(fy, r1 - r0, r0);
        maxlogit = fmaxf(maxlogit, logit);
        if (logit > 0.0f) firsthit = min(firsthit, sub + i * 8);
        tf += 8.0f;
    }

#pragma unroll
    for (int m = 4; m >= 1; m >>= 1) {
        maxlogit = fmaxf(maxlogit, __shfl_xor(maxlogit, m, 64));
        firsthit = min(firsthit, __shfl_xor(firsthit, m, 64));
    }

    // ---- RGB at first-hit point, corner-parallel across the 8 lanes ----
    const int tsel = (firsthit >= NPTS) ? 0 : firsthit;
    {
        float tt = (float)tsel * inv;
        float px = fmaf(dxr, tt, p1x);
        float py = fmaf(dyr, tt, p1y);
        float pz = fmaf(dzr, tt, p1z);
        float cx = fminf(fmaxf(fmaf(px, 0.5f, 0.5f), 0.0f), 1.0f);
        float cy = fminf(fmaxf(fmaf(py, 0.5f, 0.5f), 0.0f), 1.0f);
        float cz = fminf(fmaxf(fmaf(pz, 0.5f, 0.5f), 0.0f), 1.0f);
        const int dx = (sub >> 2) & 1, dy = (sub >> 1) & 1, dz = sub & 1;
        float feat[9];
        rgb_corner<8 >(g0, cx, cy, cz, dx, dy, dz, &feat[0]);
        rgb_corner<16>(g1, cx, cy, cz, dx, dy, dz, &feat[3]);
        rgb_corner<32>(g2, cx, cy, cz, dx, dy, dz, &feat[6]);
#pragma unroll
        for (int m = 4; m >= 1; m >>= 1) {
#pragma unroll
            for (int k = 0; k < 9; ++k)
                feat[k] += __shfl_xor(feat[k], m, 64);
        }
        if (sub == 0) {
            out_hits[ray] = 1.0f / (1.0f + __expf(-maxlogit));
#pragma unroll
            for (int c = 0; c < 3; ++c) {
                float acc = br[c];
#pragma unroll
                for (int f = 0; f < 9; ++f) acc += feat[f] * wr[f * 3 + c];
                out_rgb[ray * 3 + c] = 1.0f / (1.0f + __expf(-acc));
            }
        }
    }
}

extern "C" void kernel_launch(void* const* d_in, const int* in_sizes, int n_in,
                              void* d_out, int out_size, void* d_ws, size_t ws_size,
                              hipStream_t stream) {
    const float* x  = (const float*)d_in[0];
    const float* g0 = (const float*)d_in[1];
    const float* g1 = (const float*)d_in[2];
    const float* g2 = (const float*)d_in[3];
    const float* wl = (const float*)d_in[4];
    const float* bl = (const float*)d_in[5];
    const float* wr = (const float*)d_in[6];
    const float* br = (const float*)d_in[7];

    const int n = in_sizes[0] / 4;
    float* out_hits = (float*)d_out;
    float* out_rgb  = (float*)d_out + n;

    float4* P = (float4*)d_ws;   // NLAT*16 = 574,992 bytes of scratch

    prep_kernel<<<(NLAT + 255) / 256, 256, 0, stream>>>(g0, g1, g2, wl, bl, P);

    const int block = 256;       // 32 rays per block
    const int grid = (n * 8 + block - 1) / block;
    rays_kernel<<<grid, block, 0, stream>>>(x, P, g0, g1, g2, wr, br,
                                            out_hits, out_rgb, n);
}